// Round 4
// baseline (3581.930 us; speedup 1.0000x reference)
//
#include <hip/hip_runtime.h>

#define HID    128
#define GATES  512      // 4*HID
#define EMB    64
#define TSTEPS 1024
#define BATCH  512
#define VOCAB  50257
#define NCLS   28

typedef __attribute__((ext_vector_type(8))) short short8;   // 8 bf16 = 4 VGPRs
typedef __attribute__((ext_vector_type(4))) float f32x4;

// lgkm-only barrier: LDS visibility without draining global (vmcnt) loads.
// __syncthreads() would emit s_waitcnt vmcnt(0) and kill the gx prefetch.
#define BAR_LGKM() __asm__ __volatile__("s_waitcnt lgkmcnt(0)\n\ts_barrier" ::: "memory")

static __device__ __forceinline__ float bf2f(unsigned short u){
  union { unsigned int i; float f; } v; v.i = ((unsigned int)u) << 16; return v.f;
}
static __device__ __forceinline__ unsigned short f2bf(float f){
  union { float ff; unsigned int i; } v; v.ff = f;
  unsigned int x = v.i;
  x += 0x7fffu + ((x >> 16) & 1u);   // round-to-nearest-even
  return (unsigned short)(x >> 16);
}
static __device__ __forceinline__ float sigf(float x){
  float e = __builtin_amdgcn_exp2f(-1.44269504f * x);
  return __builtin_amdgcn_rcpf(1.f + e);
}
static __device__ __forceinline__ float tanhf_fast(float x){
  float xx = fminf(fmaxf(x, -16.f), 16.f);
  float e = __builtin_amdgcn_exp2f(-2.88539008f * xx);   // exp(-2x)
  return (1.f - e) * __builtin_amdgcn_rcpf(1.f + e);
}

// ---------------------------------------------------------------------------
// Phase 1: proj[v][g] = sum_e emb[v][e]*w_ih[g][e] + b_ih[g] + b_hh[g]
// f32 inputs; split-bf16 (hi+lo) MFMA -> f32-accurate. Unchanged (verified).
// ---------------------------------------------------------------------------
template<bool STORE_F32>
__global__ __launch_bounds__(256) void emb_proj_kernel(
    const float* __restrict__ emb,     // [V][64]
    const float* __restrict__ w_ih,    // [512][64]
    const float* __restrict__ b_ih,    // [512]
    const float* __restrict__ b_hh,    // [512]
    void* __restrict__ proj_raw)       // [V][512] f32 or bf16
{
  int wave = threadIdx.x >> 6;
  int lane = threadIdx.x & 63;
  int n = lane & 15;
  int q = lane >> 4;
  long v0 = (long)blockIdx.x * 16;

  long vrow = v0 + n; if (vrow >= VOCAB) vrow = VOCAB - 1;
  const float* er = emb + vrow * EMB;
  short8 ahi[2], alo[2];
  #pragma unroll
  for (int ch = 0; ch < 2; ++ch){
    #pragma unroll
    for (int j = 0; j < 8; ++j){
      float xv = er[ch * 32 + q * 8 + j];
      unsigned short h = f2bf(xv);
      float r = xv - bf2f(h);
      ahi[ch][j] = (short)h;
      alo[ch][j] = (short)f2bf(r);
    }
  }

  #pragma unroll
  for (int i = 0; i < 8; ++i){
    int g0 = (wave * 8 + i) * 16;
    const float* wr = w_ih + (long)(g0 + n) * EMB;
    short8 bhi[2], blo[2];
    #pragma unroll
    for (int ch = 0; ch < 2; ++ch){
      #pragma unroll
      for (int j = 0; j < 8; ++j){
        float xv = wr[ch * 32 + q * 8 + j];
        unsigned short h = f2bf(xv);
        float r = xv - bf2f(h);
        bhi[ch][j] = (short)h;
        blo[ch][j] = (short)f2bf(r);
      }
    }
    float bias = b_ih[g0 + n] + b_hh[g0 + n];
    f32x4 acc = {bias, bias, bias, bias};
    #pragma unroll
    for (int ch = 0; ch < 2; ++ch){
      acc = __builtin_amdgcn_mfma_f32_16x16x32_bf16(ahi[ch], bhi[ch], acc, 0, 0, 0);
      acc = __builtin_amdgcn_mfma_f32_16x16x32_bf16(ahi[ch], blo[ch], acc, 0, 0, 0);
      acc = __builtin_amdgcn_mfma_f32_16x16x32_bf16(alo[ch], bhi[ch], acc, 0, 0, 0);
    }
    #pragma unroll
    for (int r = 0; r < 4; ++r){
      long row = v0 + q * 4 + r;
      if (row < VOCAB){
        if (STORE_F32)
          ((float*)proj_raw)[row * GATES + g0 + n] = acc[r];
        else
          ((unsigned short*)proj_raw)[row * GATES + g0 + n] = f2bf(acc[r]);
      }
    }
  }
}

// ---------------------------------------------------------------------------
// Phase 2: LSTM recurrence + final linear. 512 blocks x 256 threads,
// 1 row/block, 2 blocks/CU. ROLE-SWAPPED MFMA: A = broadcast h (all rows
// identical), B = w_hh fragments (static in regs). D[r][n] = gate[n0+n] for
// every r -> all 4 gate types for hcol live in the owning lane's registers;
// nonlinearity is in-register, no gate LDS round trip. One lgkm-only
// barrier per step (gx prefetch survives it); depth-2 gx prefetch.
// ---------------------------------------------------------------------------
template<bool GXF32>
__global__ __launch_bounds__(256, 2) void lstm_kernel(
    const int* __restrict__ x,         // [512][1024] int32
    const float* __restrict__ w_hh,    // [512][128] f32
    const void* __restrict__ proj_raw, // [V][512] f32 or bf16 (bias folded)
    const float* __restrict__ w_lin,   // [28][128] f32
    const float* __restrict__ b_lin,   // [28] f32
    float* __restrict__ out)           // [512][28] f32
{
  __shared__ int   tok_lds[TSTEPS];        // this row's tokens (4 KB)
  __shared__ short h_lds[2][HID];          // double-buffered h (bf16 bits)

  int tid  = threadIdx.x;
  int wave = tid >> 6;
  int lane = tid & 63;
  int n = lane & 15;           // MFMA col (gate within tile)
  int q = lane >> 4;           // quad
  int sI = lane >> 5;          // this lane's s-slice (0: lanes<32, 1: >=32)
  int r0 = blockIdx.x;         // batch row

  // gather column this lane is responsible for: hcol = wave*32 + sI*16 + n
  int laneoff = wave * 32 + sI * 16 + n;

  // --- preload tokens ---------------------------------------------------
  for (int i = tid; i < TSTEPS; i += 256)
    tok_lds[i] = x[(long)r0 * TSTEPS + i];

  // --- preload B-frags: w_hh rows (f32 -> bf16), 8 tiles per wave -------
  // tile (t,s): gate base n0 = t*128 + wave*32 + s*16
  // B[k = ch*32 + q*8 + j][n] = w_hh[n0+n][k]
  short8 Bw[4][2][4];
  #pragma unroll
  for (int t = 0; t < 4; ++t)
    #pragma unroll
    for (int s = 0; s < 2; ++s){
      int n0 = t * 128 + wave * 32 + s * 16;
      const float* wr = w_hh + (long)(n0 + n) * HID;
      #pragma unroll
      for (int ch = 0; ch < 4; ++ch)
        #pragma unroll
        for (int j = 0; j < 8; ++j)
          Bw[t][s][ch][j] = (short)f2bf(wr[ch * 32 + q * 8 + j]);
    }

  // zero h buffers (h0 = 0)
  for (int i = tid; i < 2 * HID; i += 256) ((short*)h_lds)[i] = 0;

  float c_state = 0.f;                     // valid on lanes with (lane&16)==0
  bool  nlact = ((lane & 16) == 0);        // lanes 0-15 (s=0), 32-47 (s=1)

  f32x4 acc[4][2] = {};                    // reg0 re-inited per step; 1-3 don't-care

  __syncthreads();                         // tokens + h zeros (full fence OK here)

  // --- prime depth-2 gx prefetch: gxA <- step 0, gxB <- step 1 ----------
  float gxA[4], gxB[4];
  {
    int tok0 = tok_lds[0], tok1 = tok_lds[1];
    if constexpr (GXF32){
      const float* p0 = (const float*)proj_raw + (long)tok0 * GATES + laneoff;
      const float* p1 = (const float*)proj_raw + (long)tok1 * GATES + laneoff;
      #pragma unroll
      for (int t = 0; t < 4; ++t){ gxA[t] = p0[t * 128]; gxB[t] = p1[t * 128]; }
    } else {
      const unsigned short* p0 = (const unsigned short*)proj_raw + (long)tok0 * GATES + laneoff;
      const unsigned short* p1 = (const unsigned short*)proj_raw + (long)tok1 * GATES + laneoff;
      #pragma unroll
      for (int t = 0; t < 4; ++t){ gxA[t] = bf2f(p0[t * 128]); gxB[t] = bf2f(p1[t * 128]); }
    }
  }

  auto substep = [&](int step, int rb, float* gx){
    // A-frags: broadcast h; A[m][k = ch*32 + q*8 + j] = h[k] (m-independent)
    short8 Af[4];
    #pragma unroll
    for (int ch = 0; ch < 4; ++ch)
      Af[ch] = *(const short8*)(&h_lds[rb][ch * 32 + q * 8]);

    // consume gx into acc reg0 (other regs carry garbage; element-confined)
    #pragma unroll
    for (int t = 0; t < 4; ++t)
      #pragma unroll
      for (int s = 0; s < 2; ++s)
        acc[t][s][0] = gx[t];

    // re-issue prefetch for step+2 into the same buffer (in flight ~2 steps)
    {
      int nstep = step + 2 < TSTEPS ? step + 2 : TSTEPS - 1;
      int tok = tok_lds[nstep];
      if constexpr (GXF32){
        const float* pr = (const float*)proj_raw + (long)tok * GATES + laneoff;
        #pragma unroll
        for (int t = 0; t < 4; ++t) gx[t] = pr[t * 128];
      } else {
        const unsigned short* pr = (const unsigned short*)proj_raw + (long)tok * GATES + laneoff;
        #pragma unroll
        for (int t = 0; t < 4; ++t) gx[t] = bf2f(pr[t * 128]);
      }
    }

    // MFMAs: 8 tiles x 4 K-chunks; A = h broadcast, B = w_hh
    #pragma unroll
    for (int ch = 0; ch < 4; ++ch)
      #pragma unroll
      for (int t = 0; t < 4; ++t)
        #pragma unroll
        for (int s = 0; s < 2; ++s)
          acc[t][s] = __builtin_amdgcn_mfma_f32_16x16x32_bf16(
              Af[ch], Bw[t][s][ch], acc[t][s], 0, 0, 0);

    // in-register nonlinearity: lane (sI*32 + n) owns hcol wave*32+sI*16+n;
    // all four gate types are in this lane's acc[t][sI] reg0.
    if (nlact){
      float gi = sI ? acc[0][1][0] : acc[0][0][0];
      float gf = sI ? acc[1][1][0] : acc[1][0][0];
      float gg = sI ? acc[2][1][0] : acc[2][0][0];
      float go = sI ? acc[3][1][0] : acc[3][0][0];
      float si = sigf(gi), sf = sigf(gf), so = sigf(go);
      float tg = tanhf_fast(gg);
      c_state = sf * c_state + si * tg;
      float h = so * tanhf_fast(c_state);
      h_lds[rb ^ 1][laneoff] = (short)f2bf(h);
    }
    BAR_LGKM();   // LDS visibility only; gx loads stay in flight
  };

  for (int step = 0; step < TSTEPS; step += 2){
    substep(step,     0, gxA);
    substep(step + 1, 1, gxB);
  }

  // --- final linear: out[r0][j] = h . w_lin[j] + b_lin[j] --------------
  // TSTEPS even -> final h is in h_lds[0]
  if (tid < NCLS){
    int j = tid;
    float acc2 = b_lin[j];
    const float* wl = w_lin + (long)j * HID;
    #pragma unroll 4
    for (int k = 0; k < HID; ++k)
      acc2 += bf2f((unsigned short)h_lds[0][k]) * wl[k];
    out[(long)r0 * NCLS + j] = acc2;
  }
}

// ---------------------------------------------------------------------------
extern "C" void kernel_launch(void* const* d_in, const int* in_sizes, int n_in,
                              void* d_out, int out_size, void* d_ws, size_t ws_size,
                              hipStream_t stream)
{
  const int*   x     = (const int*)d_in[0];
  const float* emb   = (const float*)d_in[1];
  const float* w_ih  = (const float*)d_in[2];
  const float* w_hh  = (const float*)d_in[3];
  const float* b_ih  = (const float*)d_in[4];
  const float* b_hh  = (const float*)d_in[5];
  const float* w_lin = (const float*)d_in[6];
  const float* b_lin = (const float*)d_in[7];
  float*       out   = (float*)d_out;

  size_t need_f32 = (size_t)VOCAB * GATES * sizeof(float);   // ~103 MB
  int vblocks = (VOCAB + 15) / 16;   // 3142

  if (ws_size >= need_f32){
    emb_proj_kernel<true><<<dim3(vblocks), dim3(256), 0, stream>>>(
        emb, w_ih, b_ih, b_hh, d_ws);
    lstm_kernel<true><<<dim3(BATCH), dim3(256), 0, stream>>>(
        x, w_hh, d_ws, w_lin, b_lin, out);
  } else {
    emb_proj_kernel<false><<<dim3(vblocks), dim3(256), 0, stream>>>(
        emb, w_ih, b_ih, b_hh, d_ws);
    lstm_kernel<false><<<dim3(BATCH), dim3(256), 0, stream>>>(
        x, w_hh, d_ws, w_lin, b_lin, out);
  }
}

// Round 5
// 868.381 us; speedup vs baseline: 4.1248x; 4.1248x over previous
//
#include <hip/hip_runtime.h>

#define HID    128
#define GATES  512      // 4*HID
#define EMB    64
#define TSTEPS 1024
#define BATCH  512
#define VOCAB  50257
#define NCLS   28

typedef __attribute__((ext_vector_type(8))) short short8;   // 8 bf16 = 4 VGPRs
typedef __attribute__((ext_vector_type(4))) float f32x4;

// lgkm-only barrier: LDS visibility without draining global (vmcnt) loads.
// __syncthreads() would emit s_waitcnt vmcnt(0) and kill the gx prefetch.
#define BAR_LGKM() __asm__ __volatile__("s_waitcnt lgkmcnt(0)\n\ts_barrier" ::: "memory")

static __device__ __forceinline__ float bf2f(unsigned short u){
  union { unsigned int i; float f; } v; v.i = ((unsigned int)u) << 16; return v.f;
}
static __device__ __forceinline__ unsigned short f2bf(float f){
  union { float ff; unsigned int i; } v; v.ff = f;
  unsigned int x = v.i;
  x += 0x7fffu + ((x >> 16) & 1u);   // round-to-nearest-even
  return (unsigned short)(x >> 16);
}
static __device__ __forceinline__ float sigf(float x){
  float e = __builtin_amdgcn_exp2f(-1.44269504f * x);
  return __builtin_amdgcn_rcpf(1.f + e);
}
static __device__ __forceinline__ float tanhf_fast(float x){
  float xx = fminf(fmaxf(x, -16.f), 16.f);
  float e = __builtin_amdgcn_exp2f(-2.88539008f * xx);   // exp(-2x)
  return (1.f - e) * __builtin_amdgcn_rcpf(1.f + e);
}

// ---------------------------------------------------------------------------
// Phase 1: proj[v][g] = sum_e emb[v][e]*w_ih[g][e] + b_ih[g] + b_hh[g]
// f32 inputs; split-bf16 (hi+lo) MFMA -> f32-accurate. Unchanged (verified).
// ---------------------------------------------------------------------------
template<bool STORE_F32>
__global__ __launch_bounds__(256) void emb_proj_kernel(
    const float* __restrict__ emb,     // [V][64]
    const float* __restrict__ w_ih,    // [512][64]
    const float* __restrict__ b_ih,    // [512]
    const float* __restrict__ b_hh,    // [512]
    void* __restrict__ proj_raw)       // [V][512] f32 or bf16
{
  int wave = threadIdx.x >> 6;
  int lane = threadIdx.x & 63;
  int n = lane & 15;
  int q = lane >> 4;
  long v0 = (long)blockIdx.x * 16;

  long vrow = v0 + n; if (vrow >= VOCAB) vrow = VOCAB - 1;
  const float* er = emb + vrow * EMB;
  short8 ahi[2], alo[2];
  #pragma unroll
  for (int ch = 0; ch < 2; ++ch){
    #pragma unroll
    for (int j = 0; j < 8; ++j){
      float xv = er[ch * 32 + q * 8 + j];
      unsigned short h = f2bf(xv);
      float r = xv - bf2f(h);
      ahi[ch][j] = (short)h;
      alo[ch][j] = (short)f2bf(r);
    }
  }

  #pragma unroll
  for (int i = 0; i < 8; ++i){
    int g0 = (wave * 8 + i) * 16;
    const float* wr = w_ih + (long)(g0 + n) * EMB;
    short8 bhi[2], blo[2];
    #pragma unroll
    for (int ch = 0; ch < 2; ++ch){
      #pragma unroll
      for (int j = 0; j < 8; ++j){
        float xv = wr[ch * 32 + q * 8 + j];
        unsigned short h = f2bf(xv);
        float r = xv - bf2f(h);
        bhi[ch][j] = (short)h;
        blo[ch][j] = (short)f2bf(r);
      }
    }
    float bias = b_ih[g0 + n] + b_hh[g0 + n];
    f32x4 acc = {bias, bias, bias, bias};
    #pragma unroll
    for (int ch = 0; ch < 2; ++ch){
      acc = __builtin_amdgcn_mfma_f32_16x16x32_bf16(ahi[ch], bhi[ch], acc, 0, 0, 0);
      acc = __builtin_amdgcn_mfma_f32_16x16x32_bf16(ahi[ch], blo[ch], acc, 0, 0, 0);
      acc = __builtin_amdgcn_mfma_f32_16x16x32_bf16(alo[ch], bhi[ch], acc, 0, 0, 0);
    }
    #pragma unroll
    for (int r = 0; r < 4; ++r){
      long row = v0 + q * 4 + r;
      if (row < VOCAB){
        if (STORE_F32)
          ((float*)proj_raw)[row * GATES + g0 + n] = acc[r];
        else
          ((unsigned short*)proj_raw)[row * GATES + g0 + n] = f2bf(acc[r]);
      }
    }
  }
}

// ---------------------------------------------------------------------------
// Phase 2: LSTM recurrence + final linear. 512 blocks x 256 threads,
// 1 row/block, 2 blocks/CU. Role-swapped MFMA: A = broadcast h, B = w_hh
// (static in regs); all 4 gate types for a hcol land in the owning lane's
// acc reg0 -> in-register nonlinearity. One lgkm-only barrier per step;
// depth-2 gx prefetch in NAMED SCALAR REGISTERS (R4's float[4]-via-pointer
// was scratch-allocated -> 1.5 GB of spill traffic; macro expansion fixes).
// ---------------------------------------------------------------------------
template<bool GXF32>
__global__ __launch_bounds__(256, 2) void lstm_kernel(
    const int* __restrict__ x,         // [512][1024] int32
    const float* __restrict__ w_hh,    // [512][128] f32
    const void* __restrict__ proj_raw, // [V][512] f32 or bf16 (bias folded)
    const float* __restrict__ w_lin,   // [28][128] f32
    const float* __restrict__ b_lin,   // [28] f32
    float* __restrict__ out)           // [512][28] f32
{
  __shared__ int   tok_lds[TSTEPS];        // this row's tokens (4 KB)
  __shared__ short h_lds[2][HID];          // double-buffered h (bf16 bits)

  int tid  = threadIdx.x;
  int wave = tid >> 6;
  int lane = tid & 63;
  int n = lane & 15;           // MFMA col (gate within tile)
  int q = lane >> 4;           // quad
  int sI = lane >> 5;          // this lane's s-slice (0: lanes<32, 1: >=32)
  int r0 = blockIdx.x;         // batch row

  // hcol this lane owns for gather/nonlinearity
  int laneoff = wave * 32 + sI * 16 + n;

  // --- preload tokens ---------------------------------------------------
  for (int i = tid; i < TSTEPS; i += 256)
    tok_lds[i] = x[(long)r0 * TSTEPS + i];

  // --- preload B-frags: w_hh rows (f32 -> bf16), 8 tiles per wave -------
  // tile (t,s): gate base n0 = t*128 + wave*32 + s*16
  // B[k = ch*32 + q*8 + j][n] = w_hh[n0+n][k]
  short8 Bw[4][2][4];
  #pragma unroll
  for (int t = 0; t < 4; ++t)
    #pragma unroll
    for (int s = 0; s < 2; ++s){
      int n0 = t * 128 + wave * 32 + s * 16;
      const float* wr = w_hh + (long)(n0 + n) * HID;
      #pragma unroll
      for (int ch = 0; ch < 4; ++ch)
        #pragma unroll
        for (int j = 0; j < 8; ++j)
          Bw[t][s][ch][j] = (short)f2bf(wr[ch * 32 + q * 8 + j]);
    }

  // zero h buffers (h0 = 0)
  for (int i = tid; i < 2 * HID; i += 256) ((short*)h_lds)[i] = 0;

  float c_state = 0.f;                     // valid on lanes with (lane&16)==0
  bool  nlact = ((lane & 16) == 0);        // lanes 0-15 (s=0), 32-47 (s=1)

  f32x4 acc[4][2] = {};                    // reg0 re-inited per step

  const float*          prf = (const float*)proj_raw;
  const unsigned short* prb = (const unsigned short*)proj_raw;

  __syncthreads();                         // tokens + h zeros

  // --- depth-2 gx prefetch in named scalar registers --------------------
  float          gxA0, gxA1, gxA2, gxA3, gxB0, gxB1, gxB2, gxB3;
  unsigned short hxA0, hxA1, hxA2, hxA3, hxB0, hxB1, hxB2, hxB3;
  {
    int tok0 = tok_lds[0], tok1 = tok_lds[1];
    if constexpr (GXF32){
      const float* p0 = prf + (long)tok0 * GATES + laneoff;
      const float* p1 = prf + (long)tok1 * GATES + laneoff;
      gxA0 = p0[0]; gxA1 = p0[128]; gxA2 = p0[256]; gxA3 = p0[384];
      gxB0 = p1[0]; gxB1 = p1[128]; gxB2 = p1[256]; gxB3 = p1[384];
    } else {
      const unsigned short* p0 = prb + (long)tok0 * GATES + laneoff;
      const unsigned short* p1 = prb + (long)tok1 * GATES + laneoff;
      hxA0 = p0[0]; hxA1 = p0[128]; hxA2 = p0[256]; hxA3 = p0[384];
      hxB0 = p1[0]; hxB1 = p1[128]; hxB2 = p1[256]; hxB3 = p1[384];
    }
  }

#define SUBSTEP(RB, G0, G1, G2, G3, H0, H1, H2, H3, NSTEP)                    \
  {                                                                           \
    short8 Af[4];                                                             \
    _Pragma("unroll")                                                         \
    for (int ch = 0; ch < 4; ++ch)                                            \
      Af[ch] = *(const short8*)(&h_lds[RB][ch * 32 + q * 8]);                 \
    float g0, g1, g2, g3;                                                     \
    if constexpr (GXF32){ g0 = G0; g1 = G1; g2 = G2; g3 = G3; }               \
    else { g0 = bf2f(H0); g1 = bf2f(H1); g2 = bf2f(H2); g3 = bf2f(H3); }      \
    _Pragma("unroll")                                                         \
    for (int s = 0; s < 2; ++s){                                              \
      acc[0][s][0] = g0; acc[1][s][0] = g1;                                   \
      acc[2][s][0] = g2; acc[3][s][0] = g3;                                   \
    }                                                                         \
    {                                                                         \
      int ns = (NSTEP) < TSTEPS ? (NSTEP) : TSTEPS - 1;                       \
      int tok = tok_lds[ns];                                                  \
      if constexpr (GXF32){                                                   \
        const float* pr = prf + (long)tok * GATES + laneoff;                  \
        G0 = pr[0]; G1 = pr[128]; G2 = pr[256]; G3 = pr[384];                 \
      } else {                                                                \
        const unsigned short* pr = prb + (long)tok * GATES + laneoff;         \
        H0 = pr[0]; H1 = pr[128]; H2 = pr[256]; H3 = pr[384];                 \
      }                                                                       \
    }                                                                         \
    _Pragma("unroll")                                                         \
    for (int ch = 0; ch < 4; ++ch)                                            \
      _Pragma("unroll")                                                       \
      for (int t = 0; t < 4; ++t)                                             \
        _Pragma("unroll")                                                     \
        for (int s = 0; s < 2; ++s)                                           \
          acc[t][s] = __builtin_amdgcn_mfma_f32_16x16x32_bf16(                \
              Af[ch], Bw[t][s][ch], acc[t][s], 0, 0, 0);                      \
    if (nlact){                                                               \
      float gi = sI ? acc[0][1][0] : acc[0][0][0];                            \
      float gf = sI ? acc[1][1][0] : acc[1][0][0];                            \
      float gg = sI ? acc[2][1][0] : acc[2][0][0];                            \
      float go = sI ? acc[3][1][0] : acc[3][0][0];                            \
      float si = sigf(gi), sf = sigf(gf), so = sigf(go);                      \
      float tg = tanhf_fast(gg);                                              \
      c_state = sf * c_state + si * tg;                                       \
      float hv = so * tanhf_fast(c_state);                                    \
      h_lds[(RB) ^ 1][laneoff] = (short)f2bf(hv);                             \
    }                                                                         \
    BAR_LGKM();                                                               \
  }

  for (int step = 0; step < TSTEPS; step += 2){
    SUBSTEP(0, gxA0, gxA1, gxA2, gxA3, hxA0, hxA1, hxA2, hxA3, step + 2)
    SUBSTEP(1, gxB0, gxB1, gxB2, gxB3, hxB0, hxB1, hxB2, hxB3, step + 3)
  }
#undef SUBSTEP

  // --- final linear: out[r0][j] = h . w_lin[j] + b_lin[j] --------------
  // TSTEPS even -> final h is in h_lds[0]
  if (tid < NCLS){
    int j = tid;
    float acc2 = b_lin[j];
    const float* wl = w_lin + (long)j * HID;
    #pragma unroll 4
    for (int k = 0; k < HID; ++k)
      acc2 += bf2f((unsigned short)h_lds[0][k]) * wl[k];
    out[(long)r0 * NCLS + j] = acc2;
  }
}

// ---------------------------------------------------------------------------
extern "C" void kernel_launch(void* const* d_in, const int* in_sizes, int n_in,
                              void* d_out, int out_size, void* d_ws, size_t ws_size,
                              hipStream_t stream)
{
  const int*   x     = (const int*)d_in[0];
  const float* emb   = (const float*)d_in[1];
  const float* w_ih  = (const float*)d_in[2];
  const float* w_hh  = (const float*)d_in[3];
  const float* b_ih  = (const float*)d_in[4];
  const float* b_hh  = (const float*)d_in[5];
  const float* w_lin = (const float*)d_in[6];
  const float* b_lin = (const float*)d_in[7];
  float*       out   = (float*)d_out;

  size_t need_f32 = (size_t)VOCAB * GATES * sizeof(float);   // ~103 MB
  int vblocks = (VOCAB + 15) / 16;   // 3142

  if (ws_size >= need_f32){
    emb_proj_kernel<true><<<dim3(vblocks), dim3(256), 0, stream>>>(
        emb, w_ih, b_ih, b_hh, d_ws);
    lstm_kernel<true><<<dim3(BATCH), dim3(256), 0, stream>>>(
        x, w_hh, d_ws, w_lin, b_lin, out);
  } else {
    emb_proj_kernel<false><<<dim3(vblocks), dim3(256), 0, stream>>>(
        emb, w_ih, b_ih, b_hh, d_ws);
    lstm_kernel<false><<<dim3(BATCH), dim3(256), 0, stream>>>(
        x, w_hh, d_ws, w_lin, b_lin, out);
  }
}

// Round 6
// 790.512 us; speedup vs baseline: 4.5312x; 1.0985x over previous
//
#include <hip/hip_runtime.h>

#define HID    128
#define GATES  512      // 4*HID
#define EMB    64
#define TSTEPS 1024
#define BATCH  512
#define VOCAB  50257
#define NCLS   28

typedef __attribute__((ext_vector_type(8))) short short8;   // 8 bf16 = 4 VGPRs
typedef __attribute__((ext_vector_type(4))) float f32x4;

// lgkm-only barrier: LDS visibility without draining global (vmcnt) loads.
#define BAR_LGKM() __asm__ __volatile__("s_waitcnt lgkmcnt(0)\n\ts_barrier" ::: "memory")

static __device__ __forceinline__ float bf2f(unsigned short u){
  union { unsigned int i; float f; } v; v.i = ((unsigned int)u) << 16; return v.f;
}
static __device__ __forceinline__ unsigned short f2bf(float f){
  union { float ff; unsigned int i; } v; v.ff = f;
  unsigned int x = v.i;
  x += 0x7fffu + ((x >> 16) & 1u);   // round-to-nearest-even
  return (unsigned short)(x >> 16);
}
static __device__ __forceinline__ float sigf(float x){
  float e = __builtin_amdgcn_exp2f(-1.44269504f * x);
  return __builtin_amdgcn_rcpf(1.f + e);
}
static __device__ __forceinline__ float tanhf_fast(float x){
  float xx = fminf(fmaxf(x, -16.f), 16.f);
  float e = __builtin_amdgcn_exp2f(-2.88539008f * xx);   // exp(-2x)
  return (1.f - e) * __builtin_amdgcn_rcpf(1.f + e);
}

// ---------------------------------------------------------------------------
// Phase 1: proj[v][g] = sum_e emb[v][e]*w_ih[g][e] + b_ih[g] + b_hh[g]
// f32 inputs; split-bf16 (hi+lo) MFMA -> f32-accurate. Unchanged (verified).
// ---------------------------------------------------------------------------
template<bool STORE_F32>
__global__ __launch_bounds__(256) void emb_proj_kernel(
    const float* __restrict__ emb,     // [V][64]
    const float* __restrict__ w_ih,    // [512][64]
    const float* __restrict__ b_ih,    // [512]
    const float* __restrict__ b_hh,    // [512]
    void* __restrict__ proj_raw)       // [V][512] f32 or bf16
{
  int wave = threadIdx.x >> 6;
  int lane = threadIdx.x & 63;
  int n = lane & 15;
  int q = lane >> 4;
  long v0 = (long)blockIdx.x * 16;

  long vrow = v0 + n; if (vrow >= VOCAB) vrow = VOCAB - 1;
  const float* er = emb + vrow * EMB;
  short8 ahi[2], alo[2];
  #pragma unroll
  for (int ch = 0; ch < 2; ++ch){
    #pragma unroll
    for (int j = 0; j < 8; ++j){
      float xv = er[ch * 32 + q * 8 + j];
      unsigned short h = f2bf(xv);
      float r = xv - bf2f(h);
      ahi[ch][j] = (short)h;
      alo[ch][j] = (short)f2bf(r);
    }
  }

  #pragma unroll
  for (int i = 0; i < 8; ++i){
    int g0 = (wave * 8 + i) * 16;
    const float* wr = w_ih + (long)(g0 + n) * EMB;
    short8 bhi[2], blo[2];
    #pragma unroll
    for (int ch = 0; ch < 2; ++ch){
      #pragma unroll
      for (int j = 0; j < 8; ++j){
        float xv = wr[ch * 32 + q * 8 + j];
        unsigned short h = f2bf(xv);
        float r = xv - bf2f(h);
        bhi[ch][j] = (short)h;
        blo[ch][j] = (short)f2bf(r);
      }
    }
    float bias = b_ih[g0 + n] + b_hh[g0 + n];
    f32x4 acc = {bias, bias, bias, bias};
    #pragma unroll
    for (int ch = 0; ch < 2; ++ch){
      acc = __builtin_amdgcn_mfma_f32_16x16x32_bf16(ahi[ch], bhi[ch], acc, 0, 0, 0);
      acc = __builtin_amdgcn_mfma_f32_16x16x32_bf16(ahi[ch], blo[ch], acc, 0, 0, 0);
      acc = __builtin_amdgcn_mfma_f32_16x16x32_bf16(alo[ch], bhi[ch], acc, 0, 0, 0);
    }
    #pragma unroll
    for (int r = 0; r < 4; ++r){
      long row = v0 + q * 4 + r;
      if (row < VOCAB){
        if (STORE_F32)
          ((float*)proj_raw)[row * GATES + g0 + n] = acc[r];
        else
          ((unsigned short*)proj_raw)[row * GATES + g0 + n] = f2bf(acc[r]);
      }
    }
  }
}

// ---------------------------------------------------------------------------
// Phase 2: LSTM recurrence + final linear.
// 256 blocks x 512 threads (8 waves), R=2 batch rows per block, 1 block/CU.
// Standard orientation: A = h rows (rows 0,1 real; lanes n>=2 read dup rows,
// garbage confined to unused D rows), B = w_hh static in regs.
// Wave w covers 64 gates = hcols [w*16, w*16+16) x 4 gate types
// -> 4 N-tiles x 4 K-chunks = 16 MFMA/wave/step (vs 32 in R5: pipe halved).
// C layout: col = gate-within-tile, row = batch row -> q=0 lanes hold both
// rows' i,f,g,o for their hcol in regs 0,1 -> in-register nonlinearity.
// One lgkm-only barrier/step; depth-2 gx prefetch (const-indexed arrays).
// ---------------------------------------------------------------------------
template<bool GXF32>
__global__ __launch_bounds__(512, 2) void lstm_kernel(
    const int* __restrict__ x,         // [512][1024] int32
    const float* __restrict__ w_hh,    // [512][128] f32
    const void* __restrict__ proj_raw, // [V][512] f32 or bf16 (bias folded)
    const float* __restrict__ w_lin,   // [28][128] f32
    const float* __restrict__ b_lin,   // [28] f32
    float* __restrict__ out)           // [512][28] f32
{
  __shared__ int   tok_lds[2][TSTEPS];     // both rows' tokens (8 KB)
  __shared__ short h_lds[2][2][HID];       // [buf][row][hcol] bf16 bits

  int tid  = threadIdx.x;
  int wave = tid >> 6;          // 0..7
  int lane = tid & 63;
  int n = lane & 15;            // MFMA col (gate within tile) / A row
  int q = lane >> 4;            // quad
  int r0 = blockIdx.x * 2;      // first batch row

  // --- preload tokens (2 rows) -----------------------------------------
  for (int i = tid; i < 2 * TSTEPS; i += 512)
    ((int*)tok_lds)[i] = x[(long)r0 * TSTEPS + i];   // rows contiguous

  // --- preload B-frags: w_hh (f32 -> bf16), 4 type-tiles per wave -------
  // tile t: gate base n0 = t*128 + wave*16; B[k=ch*32+q*8+j][n] = w_hh[n0+n][k]
  short8 Bw[4][4];
  #pragma unroll
  for (int t = 0; t < 4; ++t){
    int n0 = t * 128 + wave * 16;
    const float* wr = w_hh + (long)(n0 + n) * HID;
    #pragma unroll
    for (int ch = 0; ch < 4; ++ch)
      #pragma unroll
      for (int j = 0; j < 8; ++j)
        Bw[t][ch][j] = (short)f2bf(wr[ch * 32 + q * 8 + j]);
  }

  // zero both h buffers (h0 = 0)
  for (int i = tid; i < 2 * 2 * HID; i += 512) ((short*)h_lds)[i] = 0;

  float c0 = 0.f, c1 = 0.f;              // q==0 lanes: cells for hcol wave*16+n
  bool  nlact = (q == 0);

  f32x4 acc[4] = {};                     // regs 0,1 re-inited per step

  const float*          prf = (const float*)proj_raw;
  const unsigned short* prb = (const unsigned short*)proj_raw;
  int ghcol = wave * 16 + n;             // this lane's gather gate column base

  __syncthreads();                       // tokens + h zeros

  // --- depth-2 gx prefetch: [row][t], constant-indexed (SROA-safe) ------
  float          gxA[2][4], gxB[2][4];
  unsigned short hxA[2][4], hxB[2][4];
  {
    #pragma unroll
    for (int r = 0; r < 2; ++r){
      long t0 = (long)tok_lds[r][0] * GATES + ghcol;
      long t1 = (long)tok_lds[r][1] * GATES + ghcol;
      if constexpr (GXF32){
        #pragma unroll
        for (int t = 0; t < 4; ++t){ gxA[r][t] = prf[t0 + t * 128]; gxB[r][t] = prf[t1 + t * 128]; }
      } else {
        #pragma unroll
        for (int t = 0; t < 4; ++t){ hxA[r][t] = prb[t0 + t * 128]; hxB[r][t] = prb[t1 + t * 128]; }
      }
    }
  }

#define SUBSTEP(RB, GX, HX, NSTEP)                                            \
  {                                                                           \
    short8 Af[4];                                                             \
    _Pragma("unroll")                                                         \
    for (int ch = 0; ch < 4; ++ch)                                            \
      Af[ch] = *(const short8*)(&h_lds[RB][n & 1][ch * 32 + q * 8]);          \
    _Pragma("unroll")                                                         \
    for (int t = 0; t < 4; ++t){                                              \
      if constexpr (GXF32){ acc[t][0] = GX[0][t]; acc[t][1] = GX[1][t]; }     \
      else { acc[t][0] = bf2f(HX[0][t]); acc[t][1] = bf2f(HX[1][t]); }        \
    }                                                                         \
    {                                                                         \
      int ns = (NSTEP) < TSTEPS ? (NSTEP) : TSTEPS - 1;                       \
      _Pragma("unroll")                                                       \
      for (int r = 0; r < 2; ++r){                                            \
        long base = (long)tok_lds[r][ns] * GATES + ghcol;                     \
        if constexpr (GXF32){                                                 \
          _Pragma("unroll")                                                   \
          for (int t = 0; t < 4; ++t) GX[r][t] = prf[base + t * 128];         \
        } else {                                                              \
          _Pragma("unroll")                                                   \
          for (int t = 0; t < 4; ++t) HX[r][t] = prb[base + t * 128];         \
        }                                                                     \
      }                                                                       \
    }                                                                         \
    _Pragma("unroll")                                                         \
    for (int ch = 0; ch < 4; ++ch)                                            \
      _Pragma("unroll")                                                       \
      for (int t = 0; t < 4; ++t)                                             \
        acc[t] = __builtin_amdgcn_mfma_f32_16x16x32_bf16(                     \
            Af[ch], Bw[t][ch], acc[t], 0, 0, 0);                              \
    if (nlact){                                                               \
      float si0 = sigf(acc[0][0]), sf0 = sigf(acc[1][0]), so0 = sigf(acc[3][0]); \
      float tg0 = tanhf_fast(acc[2][0]);                                      \
      float si1 = sigf(acc[0][1]), sf1 = sigf(acc[1][1]), so1 = sigf(acc[3][1]); \
      float tg1 = tanhf_fast(acc[2][1]);                                      \
      c0 = sf0 * c0 + si0 * tg0;                                              \
      c1 = sf1 * c1 + si1 * tg1;                                              \
      float h0 = so0 * tanhf_fast(c0);                                        \
      float h1 = so1 * tanhf_fast(c1);                                        \
      h_lds[(RB) ^ 1][0][ghcol] = (short)f2bf(h0);                            \
      h_lds[(RB) ^ 1][1][ghcol] = (short)f2bf(h1);                            \
    }                                                                         \
    BAR_LGKM();                                                               \
  }

  for (int step = 0; step < TSTEPS; step += 2){
    SUBSTEP(0, gxA, hxA, step + 2)
    SUBSTEP(1, gxB, hxB, step + 3)
  }
#undef SUBSTEP

  // --- final linear: out[r0+b][j] = h[b] . w_lin[j] + b_lin[j] ----------
  // TSTEPS even -> final h is in h_lds[0]
  if (tid < 2 * NCLS){
    int b = tid / NCLS, j = tid - b * NCLS;
    float acc2 = b_lin[j];
    const float* wl = w_lin + (long)j * HID;
    #pragma unroll 4
    for (int k = 0; k < HID; ++k)
      acc2 += bf2f((unsigned short)h_lds[0][b][k]) * wl[k];
    out[(long)(r0 + b) * NCLS + j] = acc2;
  }
}

// ---------------------------------------------------------------------------
extern "C" void kernel_launch(void* const* d_in, const int* in_sizes, int n_in,
                              void* d_out, int out_size, void* d_ws, size_t ws_size,
                              hipStream_t stream)
{
  const int*   x     = (const int*)d_in[0];
  const float* emb   = (const float*)d_in[1];
  const float* w_ih  = (const float*)d_in[2];
  const float* w_hh  = (const float*)d_in[3];
  const float* b_ih  = (const float*)d_in[4];
  const float* b_hh  = (const float*)d_in[5];
  const float* w_lin = (const float*)d_in[6];
  const float* b_lin = (const float*)d_in[7];
  float*       out   = (float*)d_out;

  size_t need_f32 = (size_t)VOCAB * GATES * sizeof(float);   // ~103 MB
  int vblocks = (VOCAB + 15) / 16;   // 3142

  if (ws_size >= need_f32){
    emb_proj_kernel<true><<<dim3(vblocks), dim3(256), 0, stream>>>(
        emb, w_ih, b_ih, b_hh, d_ws);
    lstm_kernel<true><<<dim3(BATCH / 2), dim3(512), 0, stream>>>(
        x, w_hh, d_ws, w_lin, b_lin, out);
  } else {
    emb_proj_kernel<false><<<dim3(vblocks), dim3(256), 0, stream>>>(
        emb, w_ih, b_ih, b_hh, d_ws);
    lstm_kernel<false><<<dim3(BATCH / 2), dim3(512), 0, stream>>>(
        x, w_hh, d_ws, w_lin, b_lin, out);
  }
}

// Round 7
// 608.654 us; speedup vs baseline: 5.8850x; 1.2988x over previous
//
#include <hip/hip_runtime.h>

#define HID    128
#define GATES  512      // 4*HID
#define EMB    64
#define TSTEPS 1024
#define BATCH  512
#define VOCAB  50257
#define NCLS   28
#define HSTRIDE 160     // h row stride in shorts: 320B = 16 banks mod 32 -> the
                        // 8 (row x quad) segments of ds_read_b128 are disjoint

typedef __attribute__((ext_vector_type(8))) short short8;   // 8 bf16 = 4 VGPRs
typedef __attribute__((ext_vector_type(4))) float f32x4;

// lgkm-only barrier: LDS visibility without draining global (vmcnt) loads.
#define BAR_LGKM() __asm__ __volatile__("s_waitcnt lgkmcnt(0)\n\ts_barrier" ::: "memory")

static __device__ __forceinline__ float bf2f(unsigned short u){
  union { unsigned int i; float f; } v; v.i = ((unsigned int)u) << 16; return v.f;
}
static __device__ __forceinline__ unsigned short f2bf(float f){
  union { float ff; unsigned int i; } v; v.ff = f;
  unsigned int x = v.i;
  x += 0x7fffu + ((x >> 16) & 1u);   // round-to-nearest-even
  return (unsigned short)(x >> 16);
}
static __device__ __forceinline__ float sigf(float x){
  float e = __builtin_amdgcn_exp2f(-1.44269504f * x);
  return __builtin_amdgcn_rcpf(1.f + e);
}
static __device__ __forceinline__ float tanhf_fast(float x){
  float xx = fminf(fmaxf(x, -16.f), 16.f);
  float e = __builtin_amdgcn_exp2f(-2.88539008f * xx);   // exp(-2x)
  return (1.f - e) * __builtin_amdgcn_rcpf(1.f + e);
}

// ---------------------------------------------------------------------------
// Phase 1: proj[v][g] = sum_e emb[v][e]*w_ih[g][e] + b_ih[g] + b_hh[g]
// f32 inputs; split-bf16 (hi+lo) MFMA -> f32-accurate. Unchanged (verified).
// ---------------------------------------------------------------------------
template<bool STORE_F32>
__global__ __launch_bounds__(256) void emb_proj_kernel(
    const float* __restrict__ emb,     // [V][64]
    const float* __restrict__ w_ih,    // [512][64]
    const float* __restrict__ b_ih,    // [512]
    const float* __restrict__ b_hh,    // [512]
    void* __restrict__ proj_raw)       // [V][512] f32 or bf16
{
  int wave = threadIdx.x >> 6;
  int lane = threadIdx.x & 63;
  int n = lane & 15;
  int q = lane >> 4;
  long v0 = (long)blockIdx.x * 16;

  long vrow = v0 + n; if (vrow >= VOCAB) vrow = VOCAB - 1;
  const float* er = emb + vrow * EMB;
  short8 ahi[2], alo[2];
  #pragma unroll
  for (int ch = 0; ch < 2; ++ch){
    #pragma unroll
    for (int j = 0; j < 8; ++j){
      float xv = er[ch * 32 + q * 8 + j];
      unsigned short h = f2bf(xv);
      float r = xv - bf2f(h);
      ahi[ch][j] = (short)h;
      alo[ch][j] = (short)f2bf(r);
    }
  }

  #pragma unroll
  for (int i = 0; i < 8; ++i){
    int g0 = (wave * 8 + i) * 16;
    const float* wr = w_ih + (long)(g0 + n) * EMB;
    short8 bhi[2], blo[2];
    #pragma unroll
    for (int ch = 0; ch < 2; ++ch){
      #pragma unroll
      for (int j = 0; j < 8; ++j){
        float xv = wr[ch * 32 + q * 8 + j];
        unsigned short h = f2bf(xv);
        float r = xv - bf2f(h);
        bhi[ch][j] = (short)h;
        blo[ch][j] = (short)f2bf(r);
      }
    }
    float bias = b_ih[g0 + n] + b_hh[g0 + n];
    f32x4 acc = {bias, bias, bias, bias};
    #pragma unroll
    for (int ch = 0; ch < 2; ++ch){
      acc = __builtin_amdgcn_mfma_f32_16x16x32_bf16(ahi[ch], bhi[ch], acc, 0, 0, 0);
      acc = __builtin_amdgcn_mfma_f32_16x16x32_bf16(ahi[ch], blo[ch], acc, 0, 0, 0);
      acc = __builtin_amdgcn_mfma_f32_16x16x32_bf16(alo[ch], bhi[ch], acc, 0, 0, 0);
    }
    #pragma unroll
    for (int r = 0; r < 4; ++r){
      long row = v0 + q * 4 + r;
      if (row < VOCAB){
        if (STORE_F32)
          ((float*)proj_raw)[row * GATES + g0 + n] = acc[r];
        else
          ((unsigned short*)proj_raw)[row * GATES + g0 + n] = f2bf(acc[r]);
      }
    }
  }
}

// ---------------------------------------------------------------------------
// Phase 2: LSTM recurrence + final linear.
// 256 blocks x 512 threads (8 waves), R=2 rows/block, 1 block/CU.
// A = h rows mapped so batch row 0 -> A-row 0, batch row 1 -> A-row 4
// (lane n reads h row (n>>2)&1): C layout then puts batch0's cell in
// q0/reg0 and batch1's in q1/reg0 -> 32 lanes own ONE cell each in reg0.
// Nonlinearity: 10 transcendentals per wave (not 20), no redistribution.
// B = w_hh static in regs; 16 MFMA/wave/step. h rows padded to HSTRIDE=160
// shorts -> conflict-free ds_read_b128. One lgkm-only barrier per step;
// depth-2 gx prefetch, each lane gathers only its own row's 4 gates.
// ---------------------------------------------------------------------------
template<bool GXF32>
__global__ __launch_bounds__(512, 2) void lstm_kernel(
    const int* __restrict__ x,         // [512][1024] int32
    const float* __restrict__ w_hh,    // [512][128] f32
    const void* __restrict__ proj_raw, // [V][512] f32 or bf16 (bias folded)
    const float* __restrict__ w_lin,   // [28][128] f32
    const float* __restrict__ b_lin,   // [28] f32
    float* __restrict__ out)           // [512][28] f32
{
  __shared__ int   tok_lds[2][TSTEPS];     // both rows' tokens (8 KB)
  __shared__ short h_lds[2][2][HSTRIDE];   // [buf][row][hcol] bf16, padded

  int tid  = threadIdx.x;
  int wave = tid >> 6;          // 0..7
  int lane = tid & 63;
  int n = lane & 15;            // MFMA col (gate within tile) / A row
  int q = lane >> 4;            // quad
  int r0 = blockIdx.x * 2;      // first batch row

  // --- preload tokens (2 rows, contiguous) ------------------------------
  for (int i = tid; i < 2 * TSTEPS; i += 512)
    ((int*)tok_lds)[i] = x[(long)r0 * TSTEPS + i];

  // --- preload B-frags: w_hh (f32 -> bf16), 4 type-tiles per wave -------
  // tile t: gate base n0 = t*128 + wave*16; B[k=ch*32+q*8+j][n] = w_hh[n0+n][k]
  short8 Bw[4][4];
  #pragma unroll
  for (int t = 0; t < 4; ++t){
    int n0 = t * 128 + wave * 16;
    const float* wr = w_hh + (long)(n0 + n) * HID;
    #pragma unroll
    for (int ch = 0; ch < 4; ++ch)
      #pragma unroll
      for (int j = 0; j < 8; ++j)
        Bw[t][ch][j] = (short)f2bf(wr[ch * 32 + q * 8 + j]);
  }

  // zero h buffers incl. pads (h0 = 0)
  for (int i = tid; i < 2 * 2 * HSTRIDE; i += 512) ((short*)h_lds)[i] = 0;

  float c_state = 0.f;                   // q<2 lanes: cell (row q, hcol)
  bool  nlact = (q < 2);
  int   arow  = (n >> 2) & 1;            // h row this lane reads for A-frag
  int   grow  = q & 1;                   // gx row this lane gathers

  f32x4 acc[4] = {};                     // reg0 re-inited per step

  const float*          prf = (const float*)proj_raw;
  const unsigned short* prb = (const unsigned short*)proj_raw;
  int ghcol = wave * 16 + n;             // this lane's gate column base

  __syncthreads();                       // tokens + h zeros

  // --- depth-2 gx prefetch: own row only, constant-indexed --------------
  float          gxA[4], gxB[4];
  unsigned short hxA[4], hxB[4];
  {
    long b0 = (long)tok_lds[grow][0] * GATES + ghcol;
    long b1 = (long)tok_lds[grow][1] * GATES + ghcol;
    if constexpr (GXF32){
      #pragma unroll
      for (int t = 0; t < 4; ++t){ gxA[t] = prf[b0 + t * 128]; gxB[t] = prf[b1 + t * 128]; }
    } else {
      #pragma unroll
      for (int t = 0; t < 4; ++t){ hxA[t] = prb[b0 + t * 128]; hxB[t] = prb[b1 + t * 128]; }
    }
  }

#define SUBSTEP(RB, GX, HX, NSTEP)                                            \
  {                                                                           \
    short8 Af[4];                                                             \
    _Pragma("unroll")                                                         \
    for (int ch = 0; ch < 4; ++ch)                                            \
      Af[ch] = *(const short8*)(&h_lds[RB][arow][ch * 32 + q * 8]);           \
    _Pragma("unroll")                                                         \
    for (int t = 0; t < 4; ++t){                                              \
      if constexpr (GXF32) acc[t][0] = GX[t];                                 \
      else                 acc[t][0] = bf2f(HX[t]);                           \
    }                                                                         \
    {                                                                         \
      int ns = (NSTEP) < TSTEPS ? (NSTEP) : TSTEPS - 1;                       \
      long base = (long)tok_lds[grow][ns] * GATES + ghcol;                    \
      if constexpr (GXF32){                                                   \
        _Pragma("unroll")                                                     \
        for (int t = 0; t < 4; ++t) GX[t] = prf[base + t * 128];              \
      } else {                                                                \
        _Pragma("unroll")                                                     \
        for (int t = 0; t < 4; ++t) HX[t] = prb[base + t * 128];              \
      }                                                                       \
    }                                                                         \
    _Pragma("unroll")                                                         \
    for (int ch = 0; ch < 4; ++ch)                                            \
      _Pragma("unroll")                                                       \
      for (int t = 0; t < 4; ++t)                                             \
        acc[t] = __builtin_amdgcn_mfma_f32_16x16x32_bf16(                     \
            Af[ch], Bw[t][ch], acc[t], 0, 0, 0);                              \
    if (nlact){                                                               \
      float si = sigf(acc[0][0]), sf = sigf(acc[1][0]), so = sigf(acc[3][0]); \
      float tg = tanhf_fast(acc[2][0]);                                       \
      c_state = sf * c_state + si * tg;                                       \
      float hv = so * tanhf_fast(c_state);                                    \
      h_lds[(RB) ^ 1][q][ghcol] = (short)f2bf(hv);                            \
    }                                                                         \
    BAR_LGKM();                                                               \
  }

  for (int step = 0; step < TSTEPS; step += 2){
    SUBSTEP(0, gxA, hxA, step + 2)
    SUBSTEP(1, gxB, hxB, step + 3)
  }
#undef SUBSTEP

  // --- final linear: out[r0+b][j] = h[b] . w_lin[j] + b_lin[j] ----------
  // TSTEPS even -> final h is in h_lds[0]
  if (tid < 2 * NCLS){
    int b = tid / NCLS, j = tid - b * NCLS;
    float acc2 = b_lin[j];
    const float* wl = w_lin + (long)j * HID;
    #pragma unroll 4
    for (int k = 0; k < HID; ++k)
      acc2 += bf2f((unsigned short)h_lds[0][b][k]) * wl[k];
    out[(long)(r0 + b) * NCLS + j] = acc2;
  }
}

// ---------------------------------------------------------------------------
extern "C" void kernel_launch(void* const* d_in, const int* in_sizes, int n_in,
                              void* d_out, int out_size, void* d_ws, size_t ws_size,
                              hipStream_t stream)
{
  const int*   x     = (const int*)d_in[0];
  const float* emb   = (const float*)d_in[1];
  const float* w_ih  = (const float*)d_in[2];
  const float* w_hh  = (const float*)d_in[3];
  const float* b_ih  = (const float*)d_in[4];
  const float* b_hh  = (const float*)d_in[5];
  const float* w_lin = (const float*)d_in[6];
  const float* b_lin = (const float*)d_in[7];
  float*       out   = (float*)d_out;

  size_t need_f32 = (size_t)VOCAB * GATES * sizeof(float);   // ~103 MB
  int vblocks = (VOCAB + 15) / 16;   // 3142

  if (ws_size >= need_f32){
    emb_proj_kernel<true><<<dim3(vblocks), dim3(256), 0, stream>>>(
        emb, w_ih, b_ih, b_hh, d_ws);
    lstm_kernel<true><<<dim3(BATCH / 2), dim3(512), 0, stream>>>(
        x, w_hh, d_ws, w_lin, b_lin, out);
  } else {
    emb_proj_kernel<false><<<dim3(vblocks), dim3(256), 0, stream>>>(
        emb, w_ih, b_ih, b_hh, d_ws);
    lstm_kernel<false><<<dim3(BATCH / 2), dim3(512), 0, stream>>>(
        x, w_hh, d_ws, w_lin, b_lin, out);
  }
}